// Round 8
// baseline (280.393 us; speedup 1.0000x reference)
//
#include <hip/hip_runtime.h>
#include <math.h>

// Fully fused quanvolution. 36->128 3x3 conv on bf16 MFMA
// (v_mfma_f32_32x32x16_bf16) as 9 shift-GEMMs, ic padded 36->48.
// M enumerated pooling-aligned: m' = cell*4 + sub -> relu+pool in-lane.
//
// Round-8 changes vs round-7:
//   * NO 27-fragment register hoist (it was 108 VGPRs -> capped occupancy at
//     3 blocks/CU and caused residual spill). Phase 3 runs in two halves
//     (mt 0..3 / mt 4..6) with acc[4]/acc[3]; B-fragments STREAM from L2
//     inside the tap loop (#pragma unroll 1 bounds in-flight regs).
//     Irreducible live ~100 regs -> __launch_bounds__(256,4), 4 blocks/CU.
//   * prep rewritten scatter-style: cls_w read COALESCED (thread = source
//     element), clsTT written scattered; padding cells zeroed by a disjoint
//     thread range. (Old gather prep cost ~30 µs in the timed graph:
//     bench-minus-steady gap 20 µs (no prep) -> 66 µs (gather prep).)
//
// d_ws:
//   [0, 110592)        bfrag [nt][t*3+ks][lane][8 bf16], zero-padded ic 36..47
//   [110592, +315392)  clsTT fp32 [k=11][nt=4][mt=7][q=4][hk=2][l31=32]
//
// LDS (27,904 B):
//   actT[256][48] bf16 (24576), slot-rotated by (row_y mod 6); xs[784]; red[48]

typedef __bf16 bf16x8 __attribute__((ext_vector_type(8)));
typedef float  f32x16 __attribute__((ext_vector_type(16)));

union Pack8 { __bf16 h[8]; uint4 v; };

__global__ __launch_bounds__(256) void prep(
    const float* __restrict__ fus_w,  // (128,36,3,3)
    const float* __restrict__ cls_w,  // (10,6272)
    const float* __restrict__ reg_w,  // (6272)
    __bf16* __restrict__ bfrag,       // 6912 * 8 bf16
    float* __restrict__ clsTT)        // 78848 floats
{
    const int gid = blockIdx.x * 256 + threadIdx.x;
    if (gid < 6912) {
        const int lane = gid & 63;
        const int rest = gid >> 6;          // 0..107
        const int m  = rest % 27;           // t*3 + ks
        const int nt = rest / 27;
        const int t  = m / 3, ks = m - t * 3;
        const int n  = nt * 32 + (lane & 31);
        const int kb = ks * 16 + (lane >> 5) * 8;
        Pack8 pk;
        #pragma unroll
        for (int j = 0; j < 8; ++j) {
            const int ic = kb + j;
            const float v = (ic < 36) ? fus_w[n * 324 + ic * 9 + t] : 0.f;
            pk.h[j] = (__bf16)v;
        }
        ((uint4*)bfrag)[gid] = pk.v;
    } else if (gid < 6912 + 68992) {
        // coalesced read, scattered write: g2 = k*6272 + f
        const int g2 = gid - 6912;
        const int k  = g2 / 6272;
        const int f  = g2 - k * 6272;
        const float v = (k < 10) ? cls_w[g2] : reg_w[f];
        const int oc   = f / 49;
        const int cell = f - oc * 49;       // < 49 always
        const int nt = oc >> 5, l31 = oc & 31;
        const int mt = cell >> 3, r = cell & 7, q = r >> 1, hk = r & 1;
        clsTT[((((k * 4 + nt) * 7 + mt) * 4 + q) * 2 + hk) * 32 + l31] = v;
    } else if (gid < 6912 + 68992 + 9856) {
        // zero the padding cells (cell = 49..55): 11 k * 128 oc * 7
        const int g3  = gid - 6912 - 68992;
        const int k   = g3 / 896;
        const int rem = g3 - k * 896;
        const int oc  = rem / 7;
        const int cell = 49 + (rem - oc * 7);
        const int nt = oc >> 5, l31 = oc & 31;
        const int mt = cell >> 3, r = cell & 7, q = r >> 1, hk = r & 1;
        clsTT[((((k * 4 + nt) * 7 + mt) * 4 + q) * 2 + hk) * 32 + l31] = 0.f;
    }
}

template<int NMT>
__device__ __forceinline__ void conv_half(
    const int mt0, const int l31, const int hk, const int nt,
    const __bf16* __restrict__ actT, const bf16x8* __restrict__ bp,
    const float fb_l, const float* __restrict__ clsTT, float* a11)
{
    int rowbase[NMT], ym6v[NMT];
    #pragma unroll
    for (int g = 0; g < NMT; ++g) {
        const int mp = (mt0 + g) * 32 + l31;
        const int cell = mp >> 2;
        const int cc = (cell < 49) ? cell : 48;   // clamp garbage rows in-bounds
        const int py = (cc * 9363) >> 16;         // cc/7 for cc<56
        const int px = cc - py * 7;
        const int yy = 2 * py + ((mp >> 1) & 1);
        const int xx = 2 * px + (mp & 1);
        rowbase[g] = yy * 16 + xx;
        ym6v[g]    = yy - 6 * ((yy * 43) >> 8);   // yy mod 6, yy < 24
    }

    f32x16 acc[NMT];
    #pragma unroll
    for (int g = 0; g < NMT; ++g)
        #pragma unroll
        for (int e = 0; e < 16; ++e) acc[g][e] = 0.f;

    #pragma unroll 1           // runtime tap loop: bounds B-frag in-flight regs
    for (int t = 0; t < 9; ++t) {
        const int ky = (t * 11) >> 5;             // t/3 for t<9
        const int kx = t - 3 * ky;
        #pragma unroll
        for (int ks = 0; ks < 3; ++ks) {
            const bf16x8 bf = bp[(t * 3 + ks) * 64];   // L2-resident stream
            #pragma unroll
            for (int g = 0; g < NMT; ++g) {
                int rot = ym6v[g] + ky; if (rot >= 6) rot -= 6;
                int slot = 2 * ks + hk + rot; if (slot >= 6) slot -= 6;
                const int row = rowbase[g] + ky * 16 + kx;
                const bf16x8 af = *(const bf16x8*)(actT + row * 48 + slot * 8);
                acc[g] = __builtin_amdgcn_mfma_f32_32x32x16_bf16(af, bf, acc[g],
                                                                 0, 0, 0);
            }
        }
    }

    // epilogue: relu+pool in-lane; coalesced clsTT fold (zeros on padding cells)
    #pragma unroll
    for (int g = 0; g < NMT; ++g) {
        const int mt = mt0 + g;
        #pragma unroll
        for (int q = 0; q < 4; ++q) {
            float pv = 0.f;
            #pragma unroll
            for (int s = 0; s < 4; ++s) {
                const float v = acc[g][q * 4 + s] + fb_l;
                pv += (v > 0.f ? v : 0.f);
            }
            pv *= 0.25f;
            const float* cw = clsTT + (((nt * 7 + mt) * 4 + q) * 2 + hk) * 32 + l31;
            #pragma unroll
            for (int k = 0; k < 11; ++k)
                a11[k] = fmaf(pv, cw[k * 7168], a11[k]);
        }
    }
}

__global__ __launch_bounds__(256, 4) void quanv_fused(
    const float* __restrict__ x,      // (B,1,28,28)
    const float* __restrict__ dw_w,   // 9
    const float* __restrict__ pw_w,   // 32
    const float* __restrict__ pw_b,   // 32
    const float* __restrict__ U,      // 16x16
    const __bf16* __restrict__ bfrag, // B fragments
    const float* __restrict__ fus_b,  // 128
    const float* __restrict__ clsTT,  // lane-ordered classifier weights
    const float* __restrict__ cls_b,  // 10
    const float* __restrict__ reg_b,  // 1
    float* __restrict__ out,          // B*10 logits, then B aux
    int B)
{
    __shared__ __align__(16) __bf16 actT[256 * 48];  // 24576 B
    __shared__ float xs[784];                        // 3136 B
    __shared__ float red[48];                        // 192 B

    const int b   = blockIdx.x;
    const int tid = threadIdx.x;
    const float* xb = x + b * 784;

    // ---- phase 0: zero actT (halo + ic padding), stage image ----
    {
        uint4 z; z.x = 0; z.y = 0; z.z = 0; z.w = 0;
        for (int i = tid; i < 1536; i += 256) ((uint4*)actT)[i] = z;
        for (int i = tid; i < 784; i += 256) xs[i] = xb[i];
    }
    __syncthreads();

    // ---- phases 1+2: per-patch work (196 patches) ----
    if (tid < 196) {
        const int i = tid / 14, j = tid % 14;
        const int Y = 2 * i, X = 2 * j;

        float w9[9];
        #pragma unroll
        for (int t = 0; t < 9; ++t) w9[t] = dw_w[t];
        float dsum = 0.f;
        #pragma unroll
        for (int dy = 0; dy < 2; ++dy) {
            #pragma unroll
            for (int dx = 0; dx < 2; ++dx) {
                const int cy = Y + dy, cx = X + dx;
                #pragma unroll
                for (int ky = 0; ky < 3; ++ky) {
                    const int yy = cy + ky - 1;
                    if (yy < 0 || yy > 27) continue;
                    #pragma unroll
                    for (int kx = 0; kx < 3; ++kx) {
                        const int xx = cx + kx - 1;
                        if (xx < 0 || xx > 27) continue;
                        dsum += xs[yy * 28 + xx] * w9[ky * 3 + kx];
                    }
                }
            }
        }
        const float dpool = 0.25f * dsum;

        // ds channels 0..31 -> row sp_o, chunks 0..3 (slot-rotated)
        const int sp_o  = (i + 1) * 16 + (j + 1);
        const int rot_o = (i + 1) % 6;           // row_y mod 6
        #pragma unroll
        for (int c8 = 0; c8 < 4; ++c8) {
            Pack8 pk;
            #pragma unroll
            for (int e = 0; e < 8; ++e)
                pk.h[e] = (__bf16)(pw_w[c8 * 8 + e] * dpool + pw_b[c8 * 8 + e]);
            int slot = c8 + rot_o; if (slot >= 6) slot -= 6;
            ((uint4*)actT)[sp_o * 6 + slot] = pk.v;
        }

        // quantum patch
        const float p0 = xs[Y * 28 + X],       p1 = xs[Y * 28 + X + 1];
        const float p2 = xs[(Y + 1) * 28 + X], p3 = xs[(Y + 1) * 28 + X + 1];
        float c0, s0, c1, s1, c2, s2, c3, s3;
        sincosf(0.5f * p0, &s0, &c0);
        sincosf(0.5f * p1, &s1, &c1);
        sincosf(0.5f * p2, &s2, &c2);
        sincosf(0.5f * p3, &s3, &c3);
        float a01[4] = {c0 * c1, c0 * s1, s0 * c1, s0 * s1};
        float a23[4] = {c2 * c3, c2 * s3, s2 * c3, s2 * s3};
        float amp[16];
        #pragma unroll
        for (int hi = 0; hi < 4; ++hi)
            #pragma unroll
            for (int lo = 0; lo < 4; ++lo)
                amp[hi * 4 + lo] = a01[hi] * a23[lo];

        float meas[4] = {0.f, 0.f, 0.f, 0.f};
        #pragma unroll
        for (int m = 0; m < 16; ++m) {
            float st = 0.f;
            #pragma unroll
            for (int n = 0; n < 16; ++n) st = fmaf(U[m * 16 + n], amp[n], st);
            const float pm = st * st;
            meas[0] += ((m >> 3) & 1) ? -pm : pm;
            meas[1] += ((m >> 2) & 1) ? -pm : pm;
            meas[2] += ((m >> 1) & 1) ? -pm : pm;
            meas[3] += (m & 1) ? -pm : pm;
        }
        const int fbase = i * 56 + j * 4;
        #pragma unroll
        for (int w = 0; w < 4; ++w) {
            const int f  = fbase + w;
            const int ch = f / 196;               // 0..3 -> ic 32+ch
            const int sp = f - ch * 196;
            const int r2 = sp / 14 + 1, c2i = sp % 14 + 1;
            const int sp2 = r2 * 16 + c2i;
            int slot = 4 + r2 % 6; if (slot >= 6) slot -= 6;
            actT[sp2 * 48 + slot * 8 + ch] = (__bf16)meas[w];
        }
    }
    __syncthreads();

    // ---- phase 3: MFMA conv in two halves (acc[4] then acc[3]) ----
    const int lane = tid & 63, nt = tid >> 6;
    const int l31  = lane & 31, hk = lane >> 5;
    const float fb_l = fus_b[nt * 32 + l31];
    const bf16x8* __restrict__ bp = ((const bf16x8*)bfrag) + (nt * 27 * 64 + lane);

    float a11[11];
    #pragma unroll
    for (int k = 0; k < 11; ++k) a11[k] = 0.f;

    conv_half<4>(0, l31, hk, nt, actT, bp, fb_l, clsTT, a11);
    conv_half<3>(4, l31, hk, nt, actT, bp, fb_l, clsTT, a11);
    __syncthreads();

    // ---- phase 4: block-reduce 11 scalars ----
    const int wv = tid >> 6;
    #pragma unroll
    for (int k = 0; k < 11; ++k) {
        float a = a11[k];
        #pragma unroll
        for (int off = 32; off > 0; off >>= 1) a += __shfl_down(a, off, 64);
        if (lane == 0) red[k * 4 + wv] = a;
    }
    __syncthreads();
    if (tid < 11) {
        const float v = red[tid * 4] + red[tid * 4 + 1] + red[tid * 4 + 2] + red[tid * 4 + 3];
        if (tid < 10) out[b * 10 + tid] = v + cls_b[tid];
        else          out[B * 10 + b]   = v + reg_b[0];
    }
}

extern "C" void kernel_launch(void* const* d_in, const int* in_sizes, int n_in,
                              void* d_out, int out_size, void* d_ws, size_t ws_size,
                              hipStream_t stream) {
    const float* x    = (const float*)d_in[0];
    const float* dw_w = (const float*)d_in[1];
    const float* pw_w = (const float*)d_in[2];
    const float* pw_b = (const float*)d_in[3];
    const float* U    = (const float*)d_in[4];
    const float* fw   = (const float*)d_in[5];
    const float* fb   = (const float*)d_in[6];
    const float* cw   = (const float*)d_in[7];
    const float* cb   = (const float*)d_in[8];
    const float* rw   = (const float*)d_in[9];
    const float* rb   = (const float*)d_in[10];
    const int B = in_sizes[0] / 784;

    __bf16* bfrag = (__bf16*)d_ws;                    // 110,592 B
    float*  clsTT = (float*)((char*)d_ws + 110592);   // 315,392 B

    prep<<<(6912 + 68992 + 9856 + 255) / 256, 256, 0, stream>>>(fw, cw, rw, bfrag, clsTT);
    quanv_fused<<<B, 256, 0, stream>>>(x, dw_w, pw_w, pw_b, U, bfrag, fb,
                                       clsTT, cb, rb, (float*)d_out, B);
}

// Round 9
// 125.118 us; speedup vs baseline: 2.2410x; 2.2410x over previous
//
#include <hip/hip_runtime.h>
#include <math.h>

// Fully fused quanvolution. 36->128 3x3 conv on bf16 MFMA
// (v_mfma_f32_32x32x16_bf16) as 9 shift-GEMMs, ic padded 36->48.
// M enumerated pooling-aligned: m' = cell*4 + sub -> relu+pool in-lane.
//
// Round-9 changes vs round-7:
//   * quanv_fused UNCHANGED (round-7 exact: 59.4 µs steady, (256,3), 27-frag
//     hoist). Round-8's (256,4) split-half variant spilled catastrophically
//     (226 MB scratch writes) — any cap below ~150 regs/wave is a no-go here.
//   * prep rewritten ONE ELEMENT PER THREAD: the old bfrag builder ran 8
//     dependent strided loads/thread on a 108-wave grid — a latency-bound
//     cold-gather plausibly worth the constant ~66 µs bench-minus-steady gap
//     seen in every round that used it (r4-r8) vs 20-34 µs before (r1-r3).
//     Now 134k threads, 1 load + 1 store each, no loops.
//
// d_ws:
//   [0, 110592)        bfrag [nt][t*3+ks][lane][8 bf16], zero-padded ic 36..47
//   [110592, +315392)  clsTT fp32 [k=11][nt=4][mt=7][q=4][hk=2][l31=32]
//
// LDS (27,904 B):
//   actT[256][48] bf16 (24576), slot-rotated by (row_y mod 6); xs[784]; red[48]

typedef __bf16 bf16x8 __attribute__((ext_vector_type(8)));
typedef float  f32x16 __attribute__((ext_vector_type(16)));

union Pack8 { __bf16 h[8]; uint4 v; };

// one element per thread: 55296 bfrag elems + 68992 clsTT elems + 9856 zeros
__global__ __launch_bounds__(256) void prep(
    const float* __restrict__ fus_w,  // (128,36,3,3)
    const float* __restrict__ cls_w,  // (10,6272)
    const float* __restrict__ reg_w,  // (6272)
    __bf16* __restrict__ bfrag,       // 55296 bf16
    float* __restrict__ clsTT)        // 78848 floats
{
    const int gid = blockIdx.x * 256 + threadIdx.x;
    if (gid < 55296) {
        // bfrag element e: frag = e>>3, j = e&7
        const int j    = gid & 7;
        const int frag = gid >> 3;
        const int lane = frag & 63;
        const int rest = frag >> 6;         // 0..107
        const int m  = rest % 27;           // t*3 + ks
        const int nt = rest / 27;
        const int t  = m / 3, ks = m - t * 3;
        const int n  = nt * 32 + (lane & 31);
        const int ic = ks * 16 + (lane >> 5) * 8 + j;
        const float v = (ic < 36) ? fus_w[n * 324 + ic * 9 + t] : 0.f;
        bfrag[gid] = (__bf16)v;             // consecutive gid -> coalesced store
    } else if (gid < 55296 + 68992) {
        // coalesced read, scattered write: g2 = k*6272 + f
        const int g2 = gid - 55296;
        const int k  = g2 / 6272;
        const int f  = g2 - k * 6272;
        const float v = (k < 10) ? cls_w[g2] : reg_w[f];
        const int oc   = f / 49;
        const int cell = f - oc * 49;       // < 49 always
        const int nt = oc >> 5, l31 = oc & 31;
        const int mt = cell >> 3, r = cell & 7, q = r >> 1, hk = r & 1;
        clsTT[((((k * 4 + nt) * 7 + mt) * 4 + q) * 2 + hk) * 32 + l31] = v;
    } else if (gid < 55296 + 68992 + 9856) {
        // zero the padding cells (cell = 49..55): 11 k * 128 oc * 7
        const int g3  = gid - 55296 - 68992;
        const int k   = g3 / 896;
        const int rem = g3 - k * 896;
        const int oc  = rem / 7;
        const int cell = 49 + (rem - oc * 7);
        const int nt = oc >> 5, l31 = oc & 31;
        const int mt = cell >> 3, r = cell & 7, q = r >> 1, hk = r & 1;
        clsTT[((((k * 4 + nt) * 7 + mt) * 4 + q) * 2 + hk) * 32 + l31] = 0.f;
    }
}

__global__ __launch_bounds__(256, 3) void quanv_fused(
    const float* __restrict__ x,      // (B,1,28,28)
    const float* __restrict__ dw_w,   // 9
    const float* __restrict__ pw_w,   // 32
    const float* __restrict__ pw_b,   // 32
    const float* __restrict__ U,      // 16x16
    const __bf16* __restrict__ bfrag, // B fragments
    const float* __restrict__ fus_b,  // 128
    const float* __restrict__ clsTT,  // lane-ordered classifier weights
    const float* __restrict__ cls_b,  // 10
    const float* __restrict__ reg_b,  // 1
    float* __restrict__ out,          // B*10 logits, then B aux
    int B)
{
    __shared__ __align__(16) __bf16 actT[256 * 48];  // 24576 B
    __shared__ float xs[784];                        // 3136 B
    __shared__ float red[48];                        // 192 B

    const int b   = blockIdx.x;
    const int tid = threadIdx.x;
    const float* xb = x + b * 784;

    // ---- phase 0: zero actT (halo + ic padding), stage image ----
    {
        uint4 z; z.x = 0; z.y = 0; z.z = 0; z.w = 0;
        for (int i = tid; i < 1536; i += 256) ((uint4*)actT)[i] = z;
        for (int i = tid; i < 784; i += 256) xs[i] = xb[i];
    }
    __syncthreads();

    // ---- phases 1+2: per-patch work (196 patches) ----
    if (tid < 196) {
        const int i = tid / 14, j = tid % 14;
        const int Y = 2 * i, X = 2 * j;

        float w9[9];
        #pragma unroll
        for (int t = 0; t < 9; ++t) w9[t] = dw_w[t];
        float dsum = 0.f;
        #pragma unroll
        for (int dy = 0; dy < 2; ++dy) {
            #pragma unroll
            for (int dx = 0; dx < 2; ++dx) {
                const int cy = Y + dy, cx = X + dx;
                #pragma unroll
                for (int ky = 0; ky < 3; ++ky) {
                    const int yy = cy + ky - 1;
                    if (yy < 0 || yy > 27) continue;
                    #pragma unroll
                    for (int kx = 0; kx < 3; ++kx) {
                        const int xx = cx + kx - 1;
                        if (xx < 0 || xx > 27) continue;
                        dsum += xs[yy * 28 + xx] * w9[ky * 3 + kx];
                    }
                }
            }
        }
        const float dpool = 0.25f * dsum;

        // ds channels 0..31 -> row sp_o, chunks 0..3 (slot-rotated)
        const int sp_o  = (i + 1) * 16 + (j + 1);
        const int rot_o = (i + 1) % 6;           // row_y mod 6
        #pragma unroll
        for (int c8 = 0; c8 < 4; ++c8) {
            Pack8 pk;
            #pragma unroll
            for (int e = 0; e < 8; ++e)
                pk.h[e] = (__bf16)(pw_w[c8 * 8 + e] * dpool + pw_b[c8 * 8 + e]);
            int slot = c8 + rot_o; if (slot >= 6) slot -= 6;
            ((uint4*)actT)[sp_o * 6 + slot] = pk.v;
        }

        // quantum patch
        const float p0 = xs[Y * 28 + X],       p1 = xs[Y * 28 + X + 1];
        const float p2 = xs[(Y + 1) * 28 + X], p3 = xs[(Y + 1) * 28 + X + 1];
        float c0, s0, c1, s1, c2, s2, c3, s3;
        sincosf(0.5f * p0, &s0, &c0);
        sincosf(0.5f * p1, &s1, &c1);
        sincosf(0.5f * p2, &s2, &c2);
        sincosf(0.5f * p3, &s3, &c3);
        float a01[4] = {c0 * c1, c0 * s1, s0 * c1, s0 * s1};
        float a23[4] = {c2 * c3, c2 * s3, s2 * c3, s2 * s3};
        float amp[16];
        #pragma unroll
        for (int hi = 0; hi < 4; ++hi)
            #pragma unroll
            for (int lo = 0; lo < 4; ++lo)
                amp[hi * 4 + lo] = a01[hi] * a23[lo];

        float meas[4] = {0.f, 0.f, 0.f, 0.f};
        #pragma unroll
        for (int m = 0; m < 16; ++m) {
            float st = 0.f;
            #pragma unroll
            for (int n = 0; n < 16; ++n) st = fmaf(U[m * 16 + n], amp[n], st);
            const float pm = st * st;
            meas[0] += ((m >> 3) & 1) ? -pm : pm;
            meas[1] += ((m >> 2) & 1) ? -pm : pm;
            meas[2] += ((m >> 1) & 1) ? -pm : pm;
            meas[3] += (m & 1) ? -pm : pm;
        }
        const int fbase = i * 56 + j * 4;
        #pragma unroll
        for (int w = 0; w < 4; ++w) {
            const int f  = fbase + w;
            const int ch = f / 196;               // 0..3 -> ic 32+ch
            const int sp = f - ch * 196;
            const int r2 = sp / 14 + 1, c2i = sp % 14 + 1;
            const int sp2 = r2 * 16 + c2i;
            int slot = 4 + r2 % 6; if (slot >= 6) slot -= 6;
            actT[sp2 * 48 + slot * 8 + ch] = (__bf16)meas[w];
        }
    }
    __syncthreads();

    // ---- phase 3: MFMA conv (9 shift-GEMMs) + in-lane pool + folded classifier ----
    const int lane = tid & 63, nt = tid >> 6;
    const int l31  = lane & 31, hk = lane >> 5;
    const float fb_l = fus_b[nt * 32 + l31];

    bf16x8 bfr[27];
    {
        const bf16x8* __restrict__ bp = ((const bf16x8*)bfrag) + (nt * 27 * 64 + lane);
        #pragma unroll
        for (int m = 0; m < 27; ++m) bfr[m] = bp[m * 64];
    }

    float a11[11];
    #pragma unroll
    for (int k = 0; k < 11; ++k) a11[k] = 0.f;

    for (int mt = 0; mt < 7; ++mt) {
        // lane's A-row: m' = mt*32 + l31 -> pooled cell + sub-pixel
        const int mp   = mt * 32 + l31;
        int cell = mp >> 2;
        const int cc = (cell < 49) ? cell : 48;   // clamp garbage rows in-bounds
        const int py = (cc * 9363) >> 16;         // cc/7 for cc<56
        const int px = cc - py * 7;
        const int yy = 2 * py + ((mp >> 1) & 1);
        const int xx = 2 * px + (mp & 1);
        const int rowbase = yy * 16 + xx;
        const int ym6 = yy - 6 * ((yy * 43) >> 8);  // yy mod 6, yy < 24

        f32x16 acc = {0.f,0.f,0.f,0.f,0.f,0.f,0.f,0.f,
                      0.f,0.f,0.f,0.f,0.f,0.f,0.f,0.f};

        #pragma unroll
        for (int t = 0; t < 9; ++t) {
            const int ky = t / 3, kx = t - ky * 3;
            int rot = ym6 + ky; if (rot >= 6) rot -= 6;
            const int row = rowbase + ky * 16 + kx;
            #pragma unroll
            for (int ks = 0; ks < 3; ++ks) {
                int slot = 2 * ks + hk + rot; if (slot >= 6) slot -= 6;
                const bf16x8 af = *(const bf16x8*)(actT + row * 48 + slot * 8);
                acc = __builtin_amdgcn_mfma_f32_32x32x16_bf16(af, bfr[t * 3 + ks],
                                                              acc, 0, 0, 0);
            }
        }

        // epilogue: relu+pool in-lane; classifier fold with coalesced clsTT
        #pragma unroll
        for (int q = 0; q < 4; ++q) {
            float pv = 0.f;
            #pragma unroll
            for (int s = 0; s < 4; ++s) {
                const float v = acc[q * 4 + s] + fb_l;
                pv += (v > 0.f ? v : 0.f);
            }
            pv *= 0.25f;
            // clsTT[k][nt][mt][q][hk][l31]; padding cells carry zero weight
            const float* cw = clsTT + (((nt * 7 + mt) * 4 + q) * 2 + hk) * 32 + l31;
            #pragma unroll
            for (int k = 0; k < 11; ++k)
                a11[k] = fmaf(pv, cw[k * 7168], a11[k]);
        }
    }
    __syncthreads();

    // ---- phase 4: block-reduce 11 scalars ----
    const int wv = tid >> 6;
    #pragma unroll
    for (int k = 0; k < 11; ++k) {
        float a = a11[k];
        #pragma unroll
        for (int off = 32; off > 0; off >>= 1) a += __shfl_down(a, off, 64);
        if (lane == 0) red[k * 4 + wv] = a;
    }
    __syncthreads();
    if (tid < 11) {
        const float v = red[tid * 4] + red[tid * 4 + 1] + red[tid * 4 + 2] + red[tid * 4 + 3];
        if (tid < 10) out[b * 10 + tid] = v + cls_b[tid];
        else          out[B * 10 + b]   = v + reg_b[0];
    }
}

extern "C" void kernel_launch(void* const* d_in, const int* in_sizes, int n_in,
                              void* d_out, int out_size, void* d_ws, size_t ws_size,
                              hipStream_t stream) {
    const float* x    = (const float*)d_in[0];
    const float* dw_w = (const float*)d_in[1];
    const float* pw_w = (const float*)d_in[2];
    const float* pw_b = (const float*)d_in[3];
    const float* U    = (const float*)d_in[4];
    const float* fw   = (const float*)d_in[5];
    const float* fb   = (const float*)d_in[6];
    const float* cw   = (const float*)d_in[7];
    const float* cb   = (const float*)d_in[8];
    const float* rw   = (const float*)d_in[9];
    const float* rb   = (const float*)d_in[10];
    const int B = in_sizes[0] / 784;

    __bf16* bfrag = (__bf16*)d_ws;                    // 110,592 B
    float*  clsTT = (float*)((char*)d_ws + 110592);   // 315,392 B

    prep<<<(55296 + 68992 + 9856 + 255) / 256, 256, 0, stream>>>(fw, cw, rw, bfrag, clsTT);
    quanv_fused<<<B, 256, 0, stream>>>(x, dw_w, pw_w, pw_b, U, bfrag, fb,
                                       clsTT, cb, rb, (float*)d_out, B);
}